// Round 7
// baseline (3338.343 us; speedup 1.0000x reference)
//
#include <hip/hip_runtime.h>
#include <hip/hip_fp16.h>
#include <math.h>

// Problem geometry (fixed by the reference)
#define BATCH   32
#define NHEAD   32
#define DIM     64
#define SEQ     4096
#define START   4080
#define NSTEPS  16
#define SCALE   0.125f

typedef float fvec4 __attribute__((ext_vector_type(4)));

// One block per (b,h) chain: 1024 blocks x 256 threads (grid-capped at
// 4 blocks/CU), 16 sequential decode steps. fp16 shadow of K/V written
// during step 0, read steps 1..15 (byte floor ~19.25 GB logical).
// Fused flash-decode pass per step (QK^T + online softmax + PV in one
// streaming loop). This round: per-GROUP (8-lane) independent online
// state -- no cross-group max shuffles per row -- and exact
// branch-on-new-max (rescale runs ~10x per pass, not 4080x). Groups
// merge once at pass end, then waves merge via LDS.
template <bool USE_WS>
__launch_bounds__(256, 4)
__global__ void attn_unroll_kernel(const float* __restrict__ x_in,
                                   const float* __restrict__ k_in,
                                   const float* __restrict__ v_in,
                                   const float* __restrict__ wq,
                                   const float* __restrict__ wk,
                                   const float* __restrict__ wv,
                                   const float* __restrict__ wo,
                                   float* __restrict__ out,
                                   __half* __restrict__ kh_ws,
                                   __half* __restrict__ vh_ws)
{
    const int bid = blockIdx.x;          // b*NHEAD + h
    const int h   = bid & (NHEAD - 1);
    const int tid = threadIdx.x;         // 0..255

    __shared__ float s_kext[NSTEPS][DIM];    // 4 KiB (cache tail, f32)
    __shared__ float s_vext[NSTEPS][DIM];    // 4 KiB
    __shared__ float s_x[DIM];
    __shared__ float s_q[DIM];
    __shared__ float s_attn[DIM];
    __shared__ float s_red[4][DIM];          // projection reduce, 1 KiB
    __shared__ float s_wacc[4][DIM];         // per-wave PV accumulators
    __shared__ float s_wm[4], s_wsum[4];     // per-wave online max / sum

    const float* __restrict__ K  = k_in + (size_t)bid * SEQ * DIM;
    const float* __restrict__ V  = v_in + (size_t)bid * SEQ * DIM;
    const float* __restrict__ Wq = wq + (size_t)h * DIM * DIM;
    const float* __restrict__ Wk = wk + (size_t)h * DIM * DIM;
    const float* __restrict__ Wv = wv + (size_t)h * DIM * DIM;
    const float* __restrict__ Wo = wo + (size_t)h * DIM * DIM;
    __half* __restrict__ Kh = USE_WS ? kh_ws + (size_t)bid * START * DIM : nullptr;
    __half* __restrict__ Vh = USE_WS ? vh_ws + (size_t)bid * START * DIM : nullptr;

    // ---- init: x vector + ext rows (original cache tail rows 4080..4095) ----
    if (tid < DIM) s_x[tid] = x_in[(size_t)bid * DIM + tid];
    for (int i = tid; i < NSTEPS * DIM; i += 256) {
        (&s_kext[0][0])[i] = K[(size_t)START * DIM + i];
        (&s_vext[0][0])[i] = V[(size_t)START * DIM + i];
    }
    __syncthreads();

    // out_vec[e] = sum_d in_vec[d] * W[d*64+e]   (einsum "d,de->e")
    auto project = [&](const float* in_vec, const float* __restrict__ W,
                       float* out_vec) {
        const int e = tid & 63;
        const int g = tid >> 6;
        float p = 0.f;
        #pragma unroll
        for (int dd = 0; dd < 16; ++dd) {
            const int d0 = g * 16 + dd;
            p += in_vec[d0] * W[d0 * 64 + e];   // coalesced over e
        }
        s_red[g][e] = p;
        __syncthreads();
        if (tid < 64)
            out_vec[tid] = s_red[0][tid] + s_red[1][tid]
                         + s_red[2][tid] + s_red[3][tid];
        __syncthreads();
    };

    const int c8   = tid & 7;    // 8 lanes per row; lane owns dims c8*8..+7
    const int rg   = tid >> 3;   // row within a 32-row tile [0,32)
    const int wave = tid >> 6;   // [0,4)

    // Per-GROUP online-softmax state (uniform across the 8 lanes of a group)
    float qv[8], acc[8], lsum, om;

    // One row's online update. p = this lane's partial dot; vv = 8 V values.
    auto online_row = [&](float p, const float* vv) {
        // broadcast the row score within the 8-lane group
        p += __shfl_xor(p, 1);
        p += __shfl_xor(p, 2);
        p += __shfl_xor(p, 4);
        if (p > om) {                      // rare: new group max
            const float f = __expf(om - p);
            lsum = lsum * f + 1.f;         // exp(p-p)==1
            #pragma unroll
            for (int j = 0; j < 8; ++j) acc[j] = acc[j] * f + vv[j];
            om = p;
        } else {                           // common path
            const float e = __expf(p - om);
            lsum += e;
            #pragma unroll
            for (int j = 0; j < 8; ++j) acc[j] += e * vv[j];
        }
    };

    // finalize: merge the 8 groups within the wave, then waves via LDS
    auto merge = [&]() {
        #pragma unroll
        for (int off = 8; off <= 32; off <<= 1) {
            const float om2 = __shfl_xor(om, off);
            const float ls2 = __shfl_xor(lsum, off);
            const float M  = fmaxf(om, om2);
            const float f1 = __expf(om - M);
            const float f2 = __expf(om2 - M);
            lsum = lsum * f1 + ls2 * f2;
            #pragma unroll
            for (int j = 0; j < 8; ++j)
                acc[j] = acc[j] * f1 + __shfl_xor(acc[j], off) * f2;
            om = M;
        }
        if ((tid & 63) == 0) { s_wm[wave] = om; s_wsum[wave] = lsum; }
        if ((tid & 63) < 8) {
            #pragma unroll
            for (int j = 0; j < 8; ++j) s_wacc[wave][c8 * 8 + j] = acc[j];
        }
        __syncthreads();
        if (tid < 64) {
            const float M = fmaxf(fmaxf(s_wm[0], s_wm[1]),
                                  fmaxf(s_wm[2], s_wm[3]));
            float tot = 0.f, val = 0.f;
            #pragma unroll
            for (int w = 0; w < 4; ++w) {
                const float f = __expf(s_wm[w] - M);
                tot += s_wsum[w] * f;
                val += s_wacc[w][tid] * f;
            }
            s_attn[tid] = val / tot;
        }
        __syncthreads();
    };

    // ext rows 4080..4095 from LDS (waves 0,1; rg in [0,16))
    auto ext_rows = [&]() {
        if (wave < 2) {
            const float* kr = s_kext[rg];
            const float* vr = s_vext[rg];
            float p = 0.f;
            #pragma unroll
            for (int j = 0; j < 8; ++j) p += kr[c8 * 8 + j] * qv[j];
            float vv[8];
            #pragma unroll
            for (int j = 0; j < 8; ++j) vv[j] = vr[c8 * 8 + j];
            online_row(p, vv);
        }
    };

    // ---- fused pass, f32 cache (step 0); emits the fp16 shadow copy ----
    auto pass_f32 = [&]() {
        #pragma unroll
        for (int j = 0; j < 8; ++j) qv[j] = s_q[c8 * 8 + j];
        #pragma unroll
        for (int j = 0; j < 8; ++j) acc[j] = 0.f;
        lsum = 0.f; om = -1e30f;
        const fvec4* __restrict__ K4 = (const fvec4*)K;
        const fvec4* __restrict__ V4 = (const fvec4*)V;
        auto row = [&](int s) {
            const fvec4 ka = K4[(size_t)s * 16 + 2 * c8];
            const fvec4 kb = K4[(size_t)s * 16 + 2 * c8 + 1];
            const fvec4 va = V4[(size_t)s * 16 + 2 * c8];
            const fvec4 vb = V4[(size_t)s * 16 + 2 * c8 + 1];
            if (USE_WS) {
                union { fvec4 v; __half2 hh[4]; } uk, uv;
                uk.hh[0] = __floats2half2_rn(ka.x, ka.y);
                uk.hh[1] = __floats2half2_rn(ka.z, ka.w);
                uk.hh[2] = __floats2half2_rn(kb.x, kb.y);
                uk.hh[3] = __floats2half2_rn(kb.z, kb.w);
                uv.hh[0] = __floats2half2_rn(va.x, va.y);
                uv.hh[1] = __floats2half2_rn(va.z, va.w);
                uv.hh[2] = __floats2half2_rn(vb.x, vb.y);
                uv.hh[3] = __floats2half2_rn(vb.z, vb.w);
                *(fvec4*)(Kh + (size_t)s * DIM + c8 * 8) = uk.v;
                *(fvec4*)(Vh + (size_t)s * DIM + c8 * 8) = uv.v;
            }
            float p = ka.x * qv[0] + ka.y * qv[1] + ka.z * qv[2] + ka.w * qv[3]
                    + kb.x * qv[4] + kb.y * qv[5] + kb.z * qv[6] + kb.w * qv[7];
            const float vv[8] = { va.x, va.y, va.z, va.w,
                                  vb.x, vb.y, vb.z, vb.w };
            online_row(p, vv);
        };
        for (int it = 0; it < 127; ++it)       // rows 0..4063
            row(it * 32 + rg);
        if (wave < 2)                          // tail rows 4064..4079
            row(4064 + rg);
        ext_rows();
        merge();
    };

    // ---- fused pass, fp16 shadow cache (steps 1..15) ----
    auto pass_h = [&]() {
        #pragma unroll
        for (int j = 0; j < 8; ++j) qv[j] = s_q[c8 * 8 + j];
        #pragma unroll
        for (int j = 0; j < 8; ++j) acc[j] = 0.f;
        lsum = 0.f; om = -1e30f;
        const fvec4* __restrict__ Kh4 = (const fvec4*)Kh;
        const fvec4* __restrict__ Vh4 = (const fvec4*)Vh;
        auto row = [&](int s) {
            fvec4 kraw = Kh4[(size_t)s * 8 + c8];
            fvec4 vraw = Vh4[(size_t)s * 8 + c8];
            const __half2* kp = (const __half2*)&kraw;
            const __half2* vp = (const __half2*)&vraw;
            float p = 0.f;
            #pragma unroll
            for (int j = 0; j < 4; ++j) {
                const float2 f = __half22float2(kp[j]);
                p += f.x * qv[2 * j] + f.y * qv[2 * j + 1];
            }
            float vv[8];
            #pragma unroll
            for (int j = 0; j < 4; ++j) {
                const float2 f = __half22float2(vp[j]);
                vv[2 * j + 0] = f.x;
                vv[2 * j + 1] = f.y;
            }
            online_row(p, vv);
        };
        for (int it = 0; it < 127; ++it)       // rows 0..4063
            row(it * 32 + rg);
        if (wave < 2)                          // tail rows 4064..4079
            row(4064 + rg);
        ext_rows();
        merge();
    };

    for (int step = 0; step < NSTEPS; ++step) {
        // ---- projections (q scaled; k_new/v_new overwrite ext row `step`) ----
        project(s_x, Wq, s_q);
        project(s_x, Wk, s_kext[step]);
        project(s_x, Wv, s_vext[step]);
        if (tid < 64) s_q[tid] *= SCALE;
        __syncthreads();

        if (USE_WS && step > 0) pass_h(); else pass_f32();

        // ---- output projection -> new x ----
        project(s_attn, Wo, s_x);
    }

    if (tid < 64) out[(size_t)bid * DIM + tid] = s_x[tid];
}

extern "C" void kernel_launch(void* const* d_in, const int* in_sizes, int n_in,
                              void* d_out, int out_size, void* d_ws, size_t ws_size,
                              hipStream_t stream) {
    const float* x  = (const float*)d_in[0];
    const float* k  = (const float*)d_in[1];
    const float* v  = (const float*)d_in[2];
    const float* wq = (const float*)d_in[3];
    const float* wk = (const float*)d_in[4];
    const float* wv = (const float*)d_in[5];
    const float* wo = (const float*)d_in[6];
    float* out = (float*)d_out;

    const size_t half_elems = (size_t)BATCH * NHEAD * START * DIM;  // per array
    const size_t need = 2 * half_elems * sizeof(__half);            // K + V

    if (ws_size >= need) {
        __half* kh = (__half*)d_ws;
        __half* vh = kh + half_elems;
        attn_unroll_kernel<true><<<BATCH * NHEAD, 256, 0, stream>>>(
            x, k, v, wq, wk, wv, wo, out, kh, vh);
    } else {
        attn_unroll_kernel<false><<<BATCH * NHEAD, 256, 0, stream>>>(
            x, k, v, wq, wk, wv, wo, out, nullptr, nullptr);
    }
}